// Round 7
// baseline (337.156 us; speedup 1.0000x reference)
//
#include <hip/hip_runtime.h>
#include <cstdint>
#include <cmath>

#define NB 16
#define AANCH 16320
#define NCLS 80
#define KPRE 1000
#define MAXDET 300
#define NCH 16            // 16 chunks of 64 >= 1000 candidates
#define CCAP 4096
#define HBINS 8192

// logit(0.05)
#define THR_LOGIT -2.9444389791664403f

// ---------------- K1: streaming max/argmax, 4 lanes per anchor, no LDS ----------------
__global__ __launch_bounds__(256) void k_score(const float* __restrict__ cls,
                                               uint32_t* __restrict__ key,
                                               int* __restrict__ label) {
    int b = blockIdx.y;
    int a0 = blockIdx.x * 64;
    int t = threadIdx.x;
    int al = t >> 2, g = t & 3;               // 4 lanes per anchor
    const float4* p = (const float4*)(cls + ((size_t)b * AANCH + a0) * NCLS) + al * 20 + g;
    float best = -3e38f; int bi = 0;
#pragma unroll
    for (int i = 0; i < 5; ++i) {             // classes c = 4g + 16i + e (ascending per thread)
        float4 v = p[4 * i];
        int c0 = 4 * g + 16 * i;
        if (v.x > best) { best = v.x; bi = c0 + 0; }
        if (v.y > best) { best = v.y; bi = c0 + 1; }
        if (v.z > best) { best = v.z; bi = c0 + 2; }
        if (v.w > best) { best = v.w; bi = c0 + 3; }
    }
#pragma unroll
    for (int m = 1; m <= 2; m <<= 1) {        // reduce 4-lane group, first-max (lowest class) wins
        float ob = __shfl_xor(best, m, 64);
        int oi = __shfl_xor(bi, m, 64);
        if (ob > best || (ob == best && oi < bi)) { best = ob; bi = oi; }
    }
    if (g == 0) {
        uint32_t k = 0;
        if (best > THR_LOGIT) {
            uint32_t ub = __float_as_uint(best);
            k = (ub & 0x80000000u) ? ~ub : (ub | 0x80000000u);  // order-preserving map
        }
        int ag = a0 + al;
        key[(size_t)b * AANCH + ag] = k;
        label[(size_t)b * AANCH + ag] = bi;
    }
}

// ------- K2: fused per-image select + rank + decode (all LDS-resident) -------
__global__ __launch_bounds__(1024, 1) void k_frd(const uint32_t* __restrict__ key,
                                                 const int* __restrict__ label,
                                                 const float* __restrict__ boxp,
                                                 const float* __restrict__ anchors,
                                                 float4* __restrict__ topBox,
                                                 float* __restrict__ topScore,
                                                 int* __restrict__ topLabel,
                                                 uint32_t* __restrict__ validCnt) {
    __shared__ uint32_t kk[AANCH];                 // 65280 B: all keys of this image
    __shared__ unsigned long long candbuf[CCAP];   // 32768 B: hist (phase A) then packed cands
    __shared__ uint32_t part[256];
    __shared__ uint32_t s_pivot, s_pos;
    uint32_t* hist = (uint32_t*)candbuf;           // 8192 bins alias the cand space
    unsigned long long* cand = candbuf;
    int b = blockIdx.x, tid = threadIdx.x;
    for (int i = tid; i < HBINS; i += 1024) hist[i] = 0;
    if (tid == 0) s_pos = 0;
    __syncthreads();
    const uint32_t* kb = key + (size_t)b * AANCH;
    for (int i = tid; i < AANCH; i += 1024) {
        uint32_t k = kb[i];
        kk[i] = k;
        atomicAdd(&hist[k >> 19], 1u);
    }
    __syncthreads();
    if (tid < 256) {
        uint32_t s = 0;
#pragma unroll
        for (int i = 0; i < 32; ++i) s += hist[tid * 32 + ((i + tid) & 31)];  // rotated: 2-way only
        part[tid] = s;
    }
    __syncthreads();
    if (tid == 0) {
        uint32_t acc = 0; int tc = 0;
        for (int t2 = 255; t2 >= 0; --t2) {
            if (acc + part[t2] >= (uint32_t)KPRE) { tc = t2; break; }
            acc += part[t2];
        }
        uint32_t p1 = 0;
        for (int bin = tc * 32 + 31; bin >= tc * 32; --bin) {
            if (acc + hist[bin] >= (uint32_t)KPRE) { p1 = (uint32_t)bin; break; }
            acc += hist[bin];
        }
        s_pivot = p1;
        uint32_t nvalid = (uint32_t)AANCH - hist[0];  // bin 0 holds exactly key==0 entries
        validCnt[b] = nvalid < (uint32_t)KPRE ? nvalid : (uint32_t)KPRE;
    }
    __syncthreads();
    uint32_t piv = s_pivot;
    // compact: cand[] clobbers hist[] (hist no longer read)
    for (int i = tid; i < AANCH; i += 1024) {
        uint32_t k = kk[i];
        if ((k >> 19) >= piv) {
            uint32_t pos = atomicAdd(&s_pos, 1u);
            if (pos < CCAP)
                cand[pos] = ((unsigned long long)k << 32) | (uint32_t)(~i);
        }
    }
    __syncthreads();
    int C = (int)(s_pos < CCAP ? s_pos : CCAP);
    // rank by counting: cand[j] read is wave-broadcast (same addr all lanes -> conflict-free)
    for (int c = tid; c < C; c += 1024) {
        unsigned long long mine = cand[c];
        uint32_t r = 0;
#pragma unroll 4
        for (int j = 0; j < C; ++j) r += (cand[j] > mine);
        if (r >= (uint32_t)KPRE) continue;
        uint32_t mk = (uint32_t)(mine >> 32);
        uint32_t idx = ~(uint32_t)mine;
        const float* an = anchors + (size_t)idx * 4;
        float a0 = an[0], a1 = an[1], a2 = an[2], a3 = an[3];
        const float* dp = boxp + ((size_t)b * AANCH + idx) * 4;
        float d0 = dp[0], d1 = dp[1], d2 = dp[2], d3 = dp[3];
        float aw = a2 - a0, ah = a3 - a1;
        float acx = a0 + 0.5f * aw, acy = a1 + 0.5f * ah;
        float cx = d0 * aw + acx, cy = d1 * ah + acy;
        float w = expf(d2) * aw, hh = expf(d3) * ah;
        float x1 = fminf(fmaxf(cx - 0.5f * w, 0.0f), 512.0f);
        float y1 = fminf(fmaxf(cy - 0.5f * hh, 0.0f), 512.0f);
        float x2 = fminf(fmaxf(cx + 0.5f * w, 0.0f), 512.0f);
        float y2 = fminf(fmaxf(cy + 0.5f * hh, 0.0f), 512.0f);
        float score;
        if (mk == 0u) {
            score = -1.0f;
        } else {
            uint32_t ub = (mk & 0x80000000u) ? (mk ^ 0x80000000u) : ~mk;
            score = 1.0f / (1.0f + expf(-__uint_as_float(ub)));
        }
        int t = b * KPRE + (int)r;
        topBox[t] = make_float4(x1, y1, x2, y2);
        topScore[t] = score;
        topLabel[t] = label[(size_t)b * AANCH + idx];
    }
}

// ------- K3: fused per-image mask build (16 waves x tiles) + greedy sweep (wave 0) -------
// maskT layout: MT[((b*NCH + src)*NCH + tgt)*64 + lane]; bit i of word = "src*64+i suppresses tgt*64+lane"
__global__ __launch_bounds__(1024, 1) void k_masknms(const float4* __restrict__ topBox,
                                                     const float* __restrict__ topScore,
                                                     const int* __restrict__ topLabel,
                                                     const uint32_t* __restrict__ validCnt,
                                                     unsigned long long* __restrict__ maskT,
                                                     float* __restrict__ out) {
    __shared__ float4 cobS[16][64];
    __shared__ float  carS[16][64];
    int b = blockIdx.x;
    int tid = threadIdx.x;
    int w = tid >> 6, lane = tid & 63;
    // ---- phase 1: 136 upper-triangular 64x64 tiles, strided over the 16 waves ----
    for (int tile = w; tile < 136; tile += 16) {
        int tt = tile, rb = 0;
        while (tt >= NCH - rb) { tt -= NCH - rb; ++rb; }
        int cb = rb + tt;
        int j = cb * 64 + lane;
        float4 vj;
        if (j < KPRE) {
            vj = topBox[b * KPRE + j];
            float off = (float)topLabel[b * KPRE + j] * 10000.0f;
            vj.x += off; vj.y += off; vj.z += off; vj.w += off;
        } else {
            vj = make_float4(-3e37f, -3e37f, -3e37f, -3e37f);
        }
        cobS[w][lane] = vj;
        carS[w][lane] = fmaxf(vj.z - vj.x, 0.0f) * fmaxf(vj.w - vj.y, 0.0f);
        int i2 = rb * 64 + lane;
        float4 bi2;
        if (i2 < KPRE) {
            bi2 = topBox[b * KPRE + i2];
            float off = (float)topLabel[b * KPRE + i2] * 10000.0f;
            bi2.x += off; bi2.y += off; bi2.z += off; bi2.w += off;
        } else {
            bi2 = make_float4(-3e37f, -3e37f, -3e37f, -3e37f);
        }
        float ai = fmaxf(bi2.z - bi2.x, 0.0f) * fmaxf(bi2.w - bi2.y, 0.0f);
        unsigned long long myword = 0;
#pragma unroll 8
        for (int jj = 0; jj < 64; ++jj) {
            int jg = cb * 64 + jj;
            float4 bj = cobS[w][jj];
            float ltx = fmaxf(bi2.x, bj.x), lty = fmaxf(bi2.y, bj.y);
            float rbx = fminf(bi2.z, bj.z), rby = fminf(bi2.w, bj.w);
            float wx = fmaxf(rbx - ltx, 0.0f), wy = fmaxf(rby - lty, 0.0f);
            float inter = wx * wy;
            float iou = inter / fmaxf(ai + carS[w][jj] - inter, 1e-6f);
            bool pred = (iou > 0.5f) && (i2 < jg) && (i2 < KPRE) && (jg < KPRE);
            unsigned long long bal = __ballot(pred);
            if (lane == jj) myword = bal;
        }
        maskT[(((size_t)b * NCH + rb) * NCH + cb) * 64 + lane] = myword;
    }
    __syncthreads();   // drains vmcnt: maskT writes visible to wave 0 via L2
    if (tid >= 64) return;
    // ---- phase 2: register-only greedy sweep, single wave ----
    int V = (int)validCnt[b];
    const unsigned long long* mtb = maskT + (size_t)b * NCH * NCH * 64;
    unsigned long long km[NCH];
#pragma unroll
    for (int s = 0; s < NCH; ++s) km[s] = 0ull;
    int count = 0;
    unsigned long long mt[NCH];
#pragma unroll
    for (int s = 0; s < NCH; ++s) mt[s] = mtb[((size_t)s * NCH + 0) * 64 + lane];
#pragma unroll
    for (int c = 0; c < NCH; ++c) {
        bool go = (c * 64 < V) && (count < MAXDET);
        unsigned long long cur[NCH];
#pragma unroll
        for (int s = 0; s < NCH; ++s) cur[s] = mt[s];
        if (go && c + 1 < NCH) {
#pragma unroll
            for (int s = 0; s < NCH; ++s) mt[s] = mtb[((size_t)s * NCH + (c + 1)) * 64 + lane];
        }
        unsigned long long kmask = 0;
        if (go) {
            unsigned long long dd = 0;
            unsigned long long colbits = cur[c];
            // cur[s] for s>c is unwritten (poison) but km[s]==0 there, so AND kills it
#pragma unroll
            for (int s = 0; s < NCH; ++s) dd |= (cur[s] & km[s]);
            bool dead = dd != 0ull;
            bool valid = (c * 64 + lane) < V;
            bool kept = false;
            while (count < MAXDET) {
                unsigned long long undec = __ballot((!dead) && (!kept) && valid);
                if (undec == 0ull) break;
                int f = __builtin_ctzll(undec);     // lowest index = next greedy keep
                kmask |= 1ull << f;
                ++count;
                if (lane == f) kept = true;
                dead = dead || (((colbits >> f) & 1ull) != 0ull);
            }
        }
        km[c] = kmask;   // uniform across lanes
    }
    int pf[NCH + 1];
    pf[0] = 0;
#pragma unroll
    for (int cc = 0; cc < NCH; ++cc) pf[cc + 1] = pf[cc] + __popcll(km[cc]);
    int total = pf[NCH];
#pragma unroll
    for (int cc = 0; cc < NCH; ++cc) {
        unsigned long long m = km[cc];
        if ((m >> lane) & 1ull) {
            int slot = pf[cc] + __popcll(m & ((1ull << lane) - 1ull));
            int g = cc * 64 + lane;
            int tdx = b * MAXDET + slot;
            float4 box = topBox[b * KPRE + g];
            out[(size_t)tdx * 4 + 0] = box.x;
            out[(size_t)tdx * 4 + 1] = box.y;
            out[(size_t)tdx * 4 + 2] = box.z;
            out[(size_t)tdx * 4 + 3] = box.w;
            out[(size_t)NB * MAXDET * 4 + tdx] = topScore[b * KPRE + g];
            out[(size_t)NB * MAXDET * 5 + tdx] = (float)(topLabel[b * KPRE + g] + 1);
        }
    }
    for (int k2 = lane; k2 < MAXDET; k2 += 64) {
        if (k2 >= total) {
            int tdx = b * MAXDET + k2;
            out[(size_t)tdx * 4 + 0] = 0.0f;
            out[(size_t)tdx * 4 + 1] = 0.0f;
            out[(size_t)tdx * 4 + 2] = 0.0f;
            out[(size_t)tdx * 4 + 3] = 0.0f;
            out[(size_t)NB * MAXDET * 4 + tdx] = 0.0f;
            out[(size_t)NB * MAXDET * 5 + tdx] = 0.0f;
        }
    }
}

extern "C" void kernel_launch(void* const* d_in, const int* in_sizes, int n_in,
                              void* d_out, int out_size, void* d_ws, size_t ws_size,
                              hipStream_t stream) {
    const float* cls = (const float*)d_in[0];
    const float* boxp = (const float*)d_in[1];
    const float* anchors = (const float*)d_in[2];
    float* out = (float*)d_out;

    char* wsp = (char*)d_ws;
    size_t off = 0;
    auto carve = [&](size_t bytes) -> void* {
        void* p = wsp + off;
        off += (bytes + 255) & ~(size_t)255;
        return p;
    };
    unsigned long long* maskT = (unsigned long long*)carve((size_t)NB * NCH * NCH * 64 * 8);
    uint32_t* key       = (uint32_t*)carve((size_t)NB * AANCH * 4);
    int*      label     = (int*)carve((size_t)NB * AANCH * 4);
    float4*   topBox    = (float4*)carve((size_t)NB * KPRE * 16);
    float*    topScore  = (float*)carve((size_t)NB * KPRE * 4);
    int*      topLabel  = (int*)carve((size_t)NB * KPRE * 4);
    uint32_t* validCnt  = (uint32_t*)carve((size_t)NB * 4);
    (void)ws_size; (void)out_size; (void)n_in; (void)in_sizes;

    k_score<<<dim3(AANCH / 64, NB), 256, 0, stream>>>(cls, key, label);
    k_frd<<<NB, 1024, 0, stream>>>(key, label, boxp, anchors, topBox, topScore, topLabel,
                                   validCnt);
    k_masknms<<<NB, 1024, 0, stream>>>(topBox, topScore, topLabel, validCnt, maskT, out);
}

// Round 8
// 226.879 us; speedup vs baseline: 1.4861x; 1.4861x over previous
//
#include <hip/hip_runtime.h>
#include <cstdint>
#include <cmath>

#define NB 16
#define AANCH 16320
#define NCLS 80
#define KPRE 1000
#define MAXDET 300
#define NCH 16            // 16 chunks of 64 >= 1000 candidates
#define CCAP 4096
#define HBINS 8192

// logit(0.05)
#define THR_LOGIT -2.9444389791664403f

// ---------------- K1: streaming max/argmax, 4 lanes per anchor, no LDS ----------------
__global__ __launch_bounds__(256) void k_score(const float* __restrict__ cls,
                                               uint32_t* __restrict__ key,
                                               int* __restrict__ label) {
    int b = blockIdx.y;
    int a0 = blockIdx.x * 64;
    int t = threadIdx.x;
    int al = t >> 2, g = t & 3;               // 4 lanes per anchor
    const float4* p = (const float4*)(cls + ((size_t)b * AANCH + a0) * NCLS) + al * 20 + g;
    float best = -3e38f; int bi = 0;
#pragma unroll
    for (int i = 0; i < 5; ++i) {             // classes c = 4g + 16i + e (ascending per thread)
        float4 v = p[4 * i];
        int c0 = 4 * g + 16 * i;
        if (v.x > best) { best = v.x; bi = c0 + 0; }
        if (v.y > best) { best = v.y; bi = c0 + 1; }
        if (v.z > best) { best = v.z; bi = c0 + 2; }
        if (v.w > best) { best = v.w; bi = c0 + 3; }
    }
#pragma unroll
    for (int m = 1; m <= 2; m <<= 1) {        // reduce 4-lane group, first-max (lowest class) wins
        float ob = __shfl_xor(best, m, 64);
        int oi = __shfl_xor(bi, m, 64);
        if (ob > best || (ob == best && oi < bi)) { best = ob; bi = oi; }
    }
    if (g == 0) {
        uint32_t k = 0;
        if (best > THR_LOGIT) {
            uint32_t ub = __float_as_uint(best);
            k = (ub & 0x80000000u) ? ~ub : (ub | 0x80000000u);  // order-preserving map
        }
        int ag = a0 + al;
        key[(size_t)b * AANCH + ag] = k;
        label[(size_t)b * AANCH + ag] = bi;
    }
}

// ------- K2: fused per-image select + rank + decode (all LDS-resident) -------
__global__ __launch_bounds__(1024, 1) void k_frd(const uint32_t* __restrict__ key,
                                                 const int* __restrict__ label,
                                                 const float* __restrict__ boxp,
                                                 const float* __restrict__ anchors,
                                                 float4* __restrict__ topBox,
                                                 float* __restrict__ topScore,
                                                 int* __restrict__ topLabel,
                                                 uint32_t* __restrict__ validCnt) {
    __shared__ uint32_t kk[AANCH];                 // 65280 B: all keys of this image
    __shared__ unsigned long long candbuf[CCAP];   // 32768 B: hist (phase A) then packed cands
    __shared__ uint32_t part[256];
    __shared__ uint32_t s_pivot, s_pos;
    uint32_t* hist = (uint32_t*)candbuf;           // 8192 bins alias the cand space
    unsigned long long* cand = candbuf;
    int b = blockIdx.x, tid = threadIdx.x;
    for (int i = tid; i < HBINS; i += 1024) hist[i] = 0;
    if (tid == 0) s_pos = 0;
    __syncthreads();
    const uint32_t* kb = key + (size_t)b * AANCH;
    for (int i = tid; i < AANCH; i += 1024) {
        uint32_t k = kb[i];
        kk[i] = k;
        atomicAdd(&hist[k >> 19], 1u);
    }
    __syncthreads();
    if (tid < 256) {
        uint32_t s = 0;
#pragma unroll
        for (int i = 0; i < 32; ++i) s += hist[tid * 32 + ((i + tid) & 31)];  // rotated: 2-way only
        part[tid] = s;
    }
    __syncthreads();
    if (tid == 0) {
        uint32_t acc = 0; int tc = 0;
        for (int t2 = 255; t2 >= 0; --t2) {
            if (acc + part[t2] >= (uint32_t)KPRE) { tc = t2; break; }
            acc += part[t2];
        }
        uint32_t p1 = 0;
        for (int bin = tc * 32 + 31; bin >= tc * 32; --bin) {
            if (acc + hist[bin] >= (uint32_t)KPRE) { p1 = (uint32_t)bin; break; }
            acc += hist[bin];
        }
        s_pivot = p1;
        uint32_t nvalid = (uint32_t)AANCH - hist[0];  // bin 0 holds exactly key==0 entries
        validCnt[b] = nvalid < (uint32_t)KPRE ? nvalid : (uint32_t)KPRE;
    }
    __syncthreads();
    uint32_t piv = s_pivot;
    // compact: cand[] clobbers hist[] (hist no longer read)
    for (int i = tid; i < AANCH; i += 1024) {
        uint32_t k = kk[i];
        if ((k >> 19) >= piv) {
            uint32_t pos = atomicAdd(&s_pos, 1u);
            if (pos < CCAP)
                cand[pos] = ((unsigned long long)k << 32) | (uint32_t)(~i);
        }
    }
    __syncthreads();
    int C = (int)(s_pos < CCAP ? s_pos : CCAP);
    // rank by counting: cand[j] read is wave-broadcast (same addr all lanes -> conflict-free)
    for (int c = tid; c < C; c += 1024) {
        unsigned long long mine = cand[c];
        uint32_t r = 0;
#pragma unroll 4
        for (int j = 0; j < C; ++j) r += (cand[j] > mine);
        if (r >= (uint32_t)KPRE) continue;
        uint32_t mk = (uint32_t)(mine >> 32);
        uint32_t idx = ~(uint32_t)mine;
        const float* an = anchors + (size_t)idx * 4;
        float a0 = an[0], a1 = an[1], a2 = an[2], a3 = an[3];
        const float* dp = boxp + ((size_t)b * AANCH + idx) * 4;
        float d0 = dp[0], d1 = dp[1], d2 = dp[2], d3 = dp[3];
        float aw = a2 - a0, ah = a3 - a1;
        float acx = a0 + 0.5f * aw, acy = a1 + 0.5f * ah;
        float cx = d0 * aw + acx, cy = d1 * ah + acy;
        float w = expf(d2) * aw, hh = expf(d3) * ah;
        float x1 = fminf(fmaxf(cx - 0.5f * w, 0.0f), 512.0f);
        float y1 = fminf(fmaxf(cy - 0.5f * hh, 0.0f), 512.0f);
        float x2 = fminf(fmaxf(cx + 0.5f * w, 0.0f), 512.0f);
        float y2 = fminf(fmaxf(cy + 0.5f * hh, 0.0f), 512.0f);
        float score;
        if (mk == 0u) {
            score = -1.0f;
        } else {
            uint32_t ub = (mk & 0x80000000u) ? (mk ^ 0x80000000u) : ~mk;
            score = 1.0f / (1.0f + expf(-__uint_as_float(ub)));
        }
        int t = b * KPRE + (int)r;
        topBox[t] = make_float4(x1, y1, x2, y2);
        topScore[t] = score;
        topLabel[t] = label[(size_t)b * AANCH + idx];
    }
}

// ---------------- K3: TRANSPOSED suppression mask via ballot (full-chip spread) ----------------
// MT[((b*NCH + src)*NCH + tgt)*64 + lane]: bit i = "cand src*64+i suppresses cand tgt*64+lane"
__global__ __launch_bounds__(64) void k_maskT(const float4* __restrict__ topBox,
                                              const int* __restrict__ topLabel,
                                              unsigned long long* __restrict__ maskT) {
    int b = blockIdx.y;
    int tt = blockIdx.x;                 // 0..135 triangular -> (rb<=cb)
    int rb = 0;
    while (tt >= NCH - rb) { tt -= NCH - rb; ++rb; }
    int cb = rb + tt;
    __shared__ float4 cob[64];
    __shared__ float car[64];
    int lane = threadIdx.x;
    int j = cb * 64 + lane;
    float4 vj;
    if (j < KPRE) {
        vj = topBox[b * KPRE + j];
        float off = (float)topLabel[b * KPRE + j] * 10000.0f;
        vj.x += off; vj.y += off; vj.z += off; vj.w += off;
    } else {
        vj = make_float4(-3e37f, -3e37f, -3e37f, -3e37f);
    }
    cob[lane] = vj;
    car[lane] = fmaxf(vj.z - vj.x, 0.0f) * fmaxf(vj.w - vj.y, 0.0f);
    int i = rb * 64 + lane;
    float4 bi;
    if (i < KPRE) {
        bi = topBox[b * KPRE + i];
        float off = (float)topLabel[b * KPRE + i] * 10000.0f;
        bi.x += off; bi.y += off; bi.z += off; bi.w += off;
    } else {
        bi = make_float4(-3e37f, -3e37f, -3e37f, -3e37f);
    }
    float ai = fmaxf(bi.z - bi.x, 0.0f) * fmaxf(bi.w - bi.y, 0.0f);
    __syncthreads();
    unsigned long long myword = 0;
#pragma unroll 8
    for (int jj = 0; jj < 64; ++jj) {
        int jg = cb * 64 + jj;
        float4 bj = cob[jj];
        float ltx = fmaxf(bi.x, bj.x), lty = fmaxf(bi.y, bj.y);
        float rbx = fminf(bi.z, bj.z), rby = fminf(bi.w, bj.w);
        float wx = fmaxf(rbx - ltx, 0.0f), wy = fmaxf(rby - lty, 0.0f);
        float inter = wx * wy;
        float iou = inter / fmaxf(ai + car[jj] - inter, 1e-6f);
        bool pred = (iou > 0.5f) && (i < jg) && (i < KPRE) && (jg < KPRE);
        unsigned long long bal = __ballot(pred);     // bit <lane> = source i suppresses target jg
        if (lane == jj) myword = bal;
    }
    maskT[(((size_t)b * NCH + rb) * NCH + cb) * 64 + lane] = myword;
}

// ---------------- K4: register-only greedy NMS + output (1 wave/image) ----------------
__global__ __launch_bounds__(64) void k_nmsout(const unsigned long long* __restrict__ maskT,
                                               const uint32_t* __restrict__ validCnt,
                                               const float4* __restrict__ topBox,
                                               const float* __restrict__ topScore,
                                               const int* __restrict__ topLabel,
                                               float* __restrict__ out) {
    int b = blockIdx.x, lane = threadIdx.x;
    int V = (int)validCnt[b];
    const unsigned long long* mtb = maskT + (size_t)b * NCH * NCH * 64;
    unsigned long long km[NCH];
#pragma unroll
    for (int s = 0; s < NCH; ++s) km[s] = 0ull;
    int count = 0;
    unsigned long long mt[NCH];
#pragma unroll
    for (int s = 0; s < NCH; ++s) mt[s] = mtb[((size_t)s * NCH + 0) * 64 + lane];
#pragma unroll
    for (int c = 0; c < NCH; ++c) {
        bool go = (c * 64 < V) && (count < MAXDET);
        unsigned long long cur[NCH];
#pragma unroll
        for (int s = 0; s < NCH; ++s) cur[s] = mt[s];
        if (go && c + 1 < NCH) {
#pragma unroll
            for (int s = 0; s < NCH; ++s) mt[s] = mtb[((size_t)s * NCH + (c + 1)) * 64 + lane];
        }
        unsigned long long kmask = 0;
        if (go) {
            unsigned long long dd = 0;
            unsigned long long colbits = cur[c];
            // cur[s] for s>c is unwritten (lower triangle) but km[s]==0 there, so AND kills it
#pragma unroll
            for (int s = 0; s < NCH; ++s) dd |= (cur[s] & km[s]);
            bool dead = dd != 0ull;
            bool valid = (c * 64 + lane) < V;
            bool kept = false;
            while (count < MAXDET) {
                unsigned long long undec = __ballot((!dead) && (!kept) && valid);
                if (undec == 0ull) break;
                int f = __builtin_ctzll(undec);     // lowest index = next greedy keep
                kmask |= 1ull << f;
                ++count;
                if (lane == f) kept = true;
                dead = dead || (((colbits >> f) & 1ull) != 0ull);
            }
        }
        km[c] = kmask;   // uniform across lanes
    }
    int pf[NCH + 1];
    pf[0] = 0;
#pragma unroll
    for (int cc = 0; cc < NCH; ++cc) pf[cc + 1] = pf[cc] + __popcll(km[cc]);
    int total = pf[NCH];
#pragma unroll
    for (int cc = 0; cc < NCH; ++cc) {
        unsigned long long m = km[cc];
        if ((m >> lane) & 1ull) {
            int slot = pf[cc] + __popcll(m & ((1ull << lane) - 1ull));
            int g = cc * 64 + lane;
            int tdx = b * MAXDET + slot;
            float4 box = topBox[b * KPRE + g];
            out[(size_t)tdx * 4 + 0] = box.x;
            out[(size_t)tdx * 4 + 1] = box.y;
            out[(size_t)tdx * 4 + 2] = box.z;
            out[(size_t)tdx * 4 + 3] = box.w;
            out[(size_t)NB * MAXDET * 4 + tdx] = topScore[b * KPRE + g];
            out[(size_t)NB * MAXDET * 5 + tdx] = (float)(topLabel[b * KPRE + g] + 1);
        }
    }
    for (int k2 = lane; k2 < MAXDET; k2 += 64) {
        if (k2 >= total) {
            int tdx = b * MAXDET + k2;
            out[(size_t)tdx * 4 + 0] = 0.0f;
            out[(size_t)tdx * 4 + 1] = 0.0f;
            out[(size_t)tdx * 4 + 2] = 0.0f;
            out[(size_t)tdx * 4 + 3] = 0.0f;
            out[(size_t)NB * MAXDET * 4 + tdx] = 0.0f;
            out[(size_t)NB * MAXDET * 5 + tdx] = 0.0f;
        }
    }
}

extern "C" void kernel_launch(void* const* d_in, const int* in_sizes, int n_in,
                              void* d_out, int out_size, void* d_ws, size_t ws_size,
                              hipStream_t stream) {
    const float* cls = (const float*)d_in[0];
    const float* boxp = (const float*)d_in[1];
    const float* anchors = (const float*)d_in[2];
    float* out = (float*)d_out;

    char* wsp = (char*)d_ws;
    size_t off = 0;
    auto carve = [&](size_t bytes) -> void* {
        void* p = wsp + off;
        off += (bytes + 255) & ~(size_t)255;
        return p;
    };
    unsigned long long* maskT = (unsigned long long*)carve((size_t)NB * NCH * NCH * 64 * 8);
    uint32_t* key       = (uint32_t*)carve((size_t)NB * AANCH * 4);
    int*      label     = (int*)carve((size_t)NB * AANCH * 4);
    float4*   topBox    = (float4*)carve((size_t)NB * KPRE * 16);
    float*    topScore  = (float*)carve((size_t)NB * KPRE * 4);
    int*      topLabel  = (int*)carve((size_t)NB * KPRE * 4);
    uint32_t* validCnt  = (uint32_t*)carve((size_t)NB * 4);
    (void)ws_size; (void)out_size; (void)n_in; (void)in_sizes;

    k_score<<<dim3(AANCH / 64, NB), 256, 0, stream>>>(cls, key, label);
    k_frd<<<NB, 1024, 0, stream>>>(key, label, boxp, anchors, topBox, topScore, topLabel,
                                   validCnt);
    k_maskT<<<dim3(136, NB), 64, 0, stream>>>(topBox, topLabel, maskT);
    k_nmsout<<<NB, 64, 0, stream>>>(maskT, validCnt, topBox, topScore, topLabel, out);
}

// Round 9
// 216.545 us; speedup vs baseline: 1.5570x; 1.0477x over previous
//
#include <hip/hip_runtime.h>
#include <cstdint>
#include <cmath>

#define NB 16
#define AANCH 16320
#define NCLS 80
#define KPRE 1000
#define MAXDET 300
#define NCH 16            // 16 chunks of 64 >= 1000 candidates
#define CCAP 4096
#define HBINS 8192

// logit(0.05)
#define THR_LOGIT -2.9444389791664403f

// ---------------- K1: streaming max/argmax, 4 lanes per anchor, no LDS ----------------
__global__ __launch_bounds__(256) void k_score(const float* __restrict__ cls,
                                               uint32_t* __restrict__ key,
                                               int* __restrict__ label) {
    int b = blockIdx.y;
    int a0 = blockIdx.x * 64;
    int t = threadIdx.x;
    int al = t >> 2, g = t & 3;               // 4 lanes per anchor
    const float4* p = (const float4*)(cls + ((size_t)b * AANCH + a0) * NCLS) + al * 20 + g;
    float best = -3e38f; int bi = 0;
#pragma unroll
    for (int i = 0; i < 5; ++i) {             // classes c = 4g + 16i + e (ascending per thread)
        float4 v = p[4 * i];
        int c0 = 4 * g + 16 * i;
        if (v.x > best) { best = v.x; bi = c0 + 0; }
        if (v.y > best) { best = v.y; bi = c0 + 1; }
        if (v.z > best) { best = v.z; bi = c0 + 2; }
        if (v.w > best) { best = v.w; bi = c0 + 3; }
    }
#pragma unroll
    for (int m = 1; m <= 2; m <<= 1) {        // reduce 4-lane group, first-max (lowest class) wins
        float ob = __shfl_xor(best, m, 64);
        int oi = __shfl_xor(bi, m, 64);
        if (ob > best || (ob == best && oi < bi)) { best = ob; bi = oi; }
    }
    if (g == 0) {
        uint32_t k = 0;
        if (best > THR_LOGIT) {
            uint32_t ub = __float_as_uint(best);
            k = (ub & 0x80000000u) ? ~ub : (ub | 0x80000000u);  // order-preserving map
        }
        int ag = a0 + al;
        key[(size_t)b * AANCH + ag] = k;
        label[(size_t)b * AANCH + ag] = bi;
    }
}

// ------- K2: per-image hist + pivot + compaction (keys staged in LDS) -------
__global__ __launch_bounds__(1024, 1) void k_fsel(const uint32_t* __restrict__ key,
                                                  uint32_t* __restrict__ validCnt,
                                                  uint32_t* __restrict__ candCount,
                                                  unsigned long long* __restrict__ cand) {
    __shared__ uint32_t kk[AANCH];     // 65280 B
    __shared__ uint32_t hist[HBINS];   // 32768 B
    __shared__ uint32_t part[256];
    __shared__ uint32_t s_pivot, s_pos;
    int b = blockIdx.x, tid = threadIdx.x;
    for (int i = tid; i < HBINS; i += 1024) hist[i] = 0;
    if (tid == 0) s_pos = 0;
    __syncthreads();
    const uint32_t* kb = key + (size_t)b * AANCH;
    for (int i = tid; i < AANCH; i += 1024) {
        uint32_t k = kb[i];
        kk[i] = k;
        atomicAdd(&hist[k >> 19], 1u);
    }
    __syncthreads();
    if (tid < 256) {
        uint32_t s = 0;
#pragma unroll
        for (int i = 0; i < 32; ++i) s += hist[tid * 32 + ((i + tid) & 31)];  // rotated: 2-way only
        part[tid] = s;
    }
    __syncthreads();
    if (tid == 0) {
        uint32_t acc = 0; int tc = 0;
        for (int t2 = 255; t2 >= 0; --t2) {
            if (acc + part[t2] >= (uint32_t)KPRE) { tc = t2; break; }
            acc += part[t2];
        }
        uint32_t p1 = 0;
        for (int bin = tc * 32 + 31; bin >= tc * 32; --bin) {
            if (acc + hist[bin] >= (uint32_t)KPRE) { p1 = (uint32_t)bin; break; }
            acc += hist[bin];
        }
        s_pivot = p1;
        uint32_t nvalid = (uint32_t)AANCH - hist[0];  // bin 0 holds exactly key==0 entries
        validCnt[b] = nvalid < (uint32_t)KPRE ? nvalid : (uint32_t)KPRE;
    }
    __syncthreads();
    uint32_t piv = s_pivot;
    for (int i = tid; i < AANCH; i += 1024) {
        uint32_t k = kk[i];
        if ((k >> 19) >= piv) {
            uint32_t pos = atomicAdd(&s_pos, 1u);
            if (pos < CCAP)
                cand[(size_t)b * CCAP + pos] = ((unsigned long long)k << 32) | (uint32_t)(~i);
        }
    }
    __syncthreads();
    if (tid == 0) candCount[b] = s_pos < CCAP ? s_pos : CCAP;
}

// ------- K3: exact rank (packed u64 desc) + decode, spread; 512 cands per block -------
__global__ __launch_bounds__(256) void k_rankdec(const unsigned long long* __restrict__ cand,
                                                 const uint32_t* __restrict__ candCount,
                                                 const int* __restrict__ label,
                                                 const float* __restrict__ boxp,
                                                 const float* __restrict__ anchors,
                                                 float4* __restrict__ topBox,
                                                 float* __restrict__ topScore,
                                                 int* __restrict__ topLabel) {
    __shared__ unsigned long long tp[2048];
    int b = blockIdx.y, tid = threadIdx.x;
    int C = (int)candCount[b];
    int base = blockIdx.x * 512;
    if (base >= C) return;                       // whole-block early exit
    const unsigned long long* cb = cand + (size_t)b * CCAP;
    int c0 = base + tid, c1 = base + 256 + tid;
    bool h0 = c0 < C, h1 = c1 < C;
    unsigned long long m0 = h0 ? cb[c0] : 0ull;
    unsigned long long m1 = h1 ? cb[c1] : 0ull;
    uint32_t r0 = 0, r1 = 0;
    for (int t0 = 0; t0 < C; t0 += 2048) {
        int n = C - t0; if (n > 2048) n = 2048;
        __syncthreads();
        for (int j = tid; j < n; j += 256) tp[j] = cb[t0 + j];
        __syncthreads();
#pragma unroll 4
        for (int j = 0; j < n; ++j) {
            unsigned long long v = tp[j];
            r0 += (v > m0);
            r1 += (v > m1);
        }
    }
#pragma unroll
    for (int q = 0; q < 2; ++q) {
        bool h = q == 0 ? h0 : h1;
        uint32_t r = q == 0 ? r0 : r1;
        unsigned long long mine = q == 0 ? m0 : m1;
        if (!h || r >= (uint32_t)KPRE) continue;
        uint32_t mk = (uint32_t)(mine >> 32);
        uint32_t idx = ~(uint32_t)mine;
        const float* an = anchors + (size_t)idx * 4;
        float a0 = an[0], a1 = an[1], a2 = an[2], a3 = an[3];
        const float* dp = boxp + ((size_t)b * AANCH + idx) * 4;
        float d0 = dp[0], d1 = dp[1], d2 = dp[2], d3 = dp[3];
        float aw = a2 - a0, ah = a3 - a1;
        float acx = a0 + 0.5f * aw, acy = a1 + 0.5f * ah;
        float cx = d0 * aw + acx, cy = d1 * ah + acy;
        float w = expf(d2) * aw, hh = expf(d3) * ah;
        float x1 = fminf(fmaxf(cx - 0.5f * w, 0.0f), 512.0f);
        float y1 = fminf(fmaxf(cy - 0.5f * hh, 0.0f), 512.0f);
        float x2 = fminf(fmaxf(cx + 0.5f * w, 0.0f), 512.0f);
        float y2 = fminf(fmaxf(cy + 0.5f * hh, 0.0f), 512.0f);
        float score;
        if (mk == 0u) {
            score = -1.0f;
        } else {
            uint32_t ub = (mk & 0x80000000u) ? (mk ^ 0x80000000u) : ~mk;
            score = 1.0f / (1.0f + expf(-__uint_as_float(ub)));
        }
        int t = b * KPRE + (int)r;
        topBox[t] = make_float4(x1, y1, x2, y2);
        topScore[t] = score;
        topLabel[t] = label[(size_t)b * AANCH + idx];
    }
}

// ---------------- K4: TRANSPOSED suppression mask via ballot (full-chip spread) ----------------
// MT[((b*NCH + src)*NCH + tgt)*64 + lane]: bit i = "cand src*64+i suppresses cand tgt*64+lane"
__global__ __launch_bounds__(64) void k_maskT(const float4* __restrict__ topBox,
                                              const int* __restrict__ topLabel,
                                              unsigned long long* __restrict__ maskT) {
    int b = blockIdx.y;
    int tt = blockIdx.x;                 // 0..135 triangular -> (rb<=cb)
    int rb = 0;
    while (tt >= NCH - rb) { tt -= NCH - rb; ++rb; }
    int cb = rb + tt;
    __shared__ float4 cob[64];
    __shared__ float car[64];
    int lane = threadIdx.x;
    int j = cb * 64 + lane;
    float4 vj;
    if (j < KPRE) {
        vj = topBox[b * KPRE + j];
        float off = (float)topLabel[b * KPRE + j] * 10000.0f;
        vj.x += off; vj.y += off; vj.z += off; vj.w += off;
    } else {
        vj = make_float4(-3e37f, -3e37f, -3e37f, -3e37f);
    }
    cob[lane] = vj;
    car[lane] = fmaxf(vj.z - vj.x, 0.0f) * fmaxf(vj.w - vj.y, 0.0f);
    int i = rb * 64 + lane;
    float4 bi;
    if (i < KPRE) {
        bi = topBox[b * KPRE + i];
        float off = (float)topLabel[b * KPRE + i] * 10000.0f;
        bi.x += off; bi.y += off; bi.z += off; bi.w += off;
    } else {
        bi = make_float4(-3e37f, -3e37f, -3e37f, -3e37f);
    }
    float ai = fmaxf(bi.z - bi.x, 0.0f) * fmaxf(bi.w - bi.y, 0.0f);
    __syncthreads();
    unsigned long long myword = 0;
#pragma unroll 8
    for (int jj = 0; jj < 64; ++jj) {
        int jg = cb * 64 + jj;
        float4 bj = cob[jj];
        float ltx = fmaxf(bi.x, bj.x), lty = fmaxf(bi.y, bj.y);
        float rbx = fminf(bi.z, bj.z), rby = fminf(bi.w, bj.w);
        float wx = fmaxf(rbx - ltx, 0.0f), wy = fmaxf(rby - lty, 0.0f);
        float inter = wx * wy;
        float iou = inter / fmaxf(ai + car[jj] - inter, 1e-6f);
        bool pred = (iou > 0.5f) && (i < jg) && (i < KPRE) && (jg < KPRE);
        unsigned long long bal = __ballot(pred);     // bit <lane> = source i suppresses target jg
        if (lane == jj) myword = bal;
    }
    maskT[(((size_t)b * NCH + rb) * NCH + cb) * 64 + lane] = myword;
}

// ---------------- K5: register-only greedy NMS + output (1 wave/image) ----------------
__global__ __launch_bounds__(64) void k_nmsout(const unsigned long long* __restrict__ maskT,
                                               const uint32_t* __restrict__ validCnt,
                                               const float4* __restrict__ topBox,
                                               const float* __restrict__ topScore,
                                               const int* __restrict__ topLabel,
                                               float* __restrict__ out) {
    int b = blockIdx.x, lane = threadIdx.x;
    int V = (int)validCnt[b];
    const unsigned long long* mtb = maskT + (size_t)b * NCH * NCH * 64;
    unsigned long long km[NCH];
#pragma unroll
    for (int s = 0; s < NCH; ++s) km[s] = 0ull;
    int count = 0;
    unsigned long long mt[NCH];
#pragma unroll
    for (int s = 0; s < NCH; ++s) mt[s] = mtb[((size_t)s * NCH + 0) * 64 + lane];
#pragma unroll
    for (int c = 0; c < NCH; ++c) {
        bool go = (c * 64 < V) && (count < MAXDET);
        unsigned long long cur[NCH];
#pragma unroll
        for (int s = 0; s < NCH; ++s) cur[s] = mt[s];
        if (go && c + 1 < NCH) {
#pragma unroll
            for (int s = 0; s < NCH; ++s) mt[s] = mtb[((size_t)s * NCH + (c + 1)) * 64 + lane];
        }
        unsigned long long kmask = 0;
        if (go) {
            unsigned long long dd = 0;
            unsigned long long colbits = cur[c];
            // cur[s] for s>c is unwritten (lower triangle) but km[s]==0 there, so AND kills it
#pragma unroll
            for (int s = 0; s < NCH; ++s) dd |= (cur[s] & km[s]);
            bool dead = dd != 0ull;
            bool valid = (c * 64 + lane) < V;
            bool kept = false;
            while (count < MAXDET) {
                unsigned long long undec = __ballot((!dead) && (!kept) && valid);
                if (undec == 0ull) break;
                int f = __builtin_ctzll(undec);     // lowest index = next greedy keep
                kmask |= 1ull << f;
                ++count;
                if (lane == f) kept = true;
                dead = dead || (((colbits >> f) & 1ull) != 0ull);
            }
        }
        km[c] = kmask;   // uniform across lanes
    }
    int pf[NCH + 1];
    pf[0] = 0;
#pragma unroll
    for (int cc = 0; cc < NCH; ++cc) pf[cc + 1] = pf[cc] + __popcll(km[cc]);
    int total = pf[NCH];
#pragma unroll
    for (int cc = 0; cc < NCH; ++cc) {
        unsigned long long m = km[cc];
        if ((m >> lane) & 1ull) {
            int slot = pf[cc] + __popcll(m & ((1ull << lane) - 1ull));
            int g = cc * 64 + lane;
            int tdx = b * MAXDET + slot;
            float4 box = topBox[b * KPRE + g];
            out[(size_t)tdx * 4 + 0] = box.x;
            out[(size_t)tdx * 4 + 1] = box.y;
            out[(size_t)tdx * 4 + 2] = box.z;
            out[(size_t)tdx * 4 + 3] = box.w;
            out[(size_t)NB * MAXDET * 4 + tdx] = topScore[b * KPRE + g];
            out[(size_t)NB * MAXDET * 5 + tdx] = (float)(topLabel[b * KPRE + g] + 1);
        }
    }
    for (int k2 = lane; k2 < MAXDET; k2 += 64) {
        if (k2 >= total) {
            int tdx = b * MAXDET + k2;
            out[(size_t)tdx * 4 + 0] = 0.0f;
            out[(size_t)tdx * 4 + 1] = 0.0f;
            out[(size_t)tdx * 4 + 2] = 0.0f;
            out[(size_t)tdx * 4 + 3] = 0.0f;
            out[(size_t)NB * MAXDET * 4 + tdx] = 0.0f;
            out[(size_t)NB * MAXDET * 5 + tdx] = 0.0f;
        }
    }
}

extern "C" void kernel_launch(void* const* d_in, const int* in_sizes, int n_in,
                              void* d_out, int out_size, void* d_ws, size_t ws_size,
                              hipStream_t stream) {
    const float* cls = (const float*)d_in[0];
    const float* boxp = (const float*)d_in[1];
    const float* anchors = (const float*)d_in[2];
    float* out = (float*)d_out;

    char* wsp = (char*)d_ws;
    size_t off = 0;
    auto carve = [&](size_t bytes) -> void* {
        void* p = wsp + off;
        off += (bytes + 255) & ~(size_t)255;
        return p;
    };
    unsigned long long* maskT = (unsigned long long*)carve((size_t)NB * NCH * NCH * 64 * 8);
    uint32_t* key       = (uint32_t*)carve((size_t)NB * AANCH * 4);
    int*      label     = (int*)carve((size_t)NB * AANCH * 4);
    unsigned long long* cand = (unsigned long long*)carve((size_t)NB * CCAP * 8);
    float4*   topBox    = (float4*)carve((size_t)NB * KPRE * 16);
    float*    topScore  = (float*)carve((size_t)NB * KPRE * 4);
    int*      topLabel  = (int*)carve((size_t)NB * KPRE * 4);
    uint32_t* validCnt  = (uint32_t*)carve((size_t)NB * 4);
    uint32_t* candCount = (uint32_t*)carve((size_t)NB * 4);
    (void)ws_size; (void)out_size; (void)n_in; (void)in_sizes;

    k_score<<<dim3(AANCH / 64, NB), 256, 0, stream>>>(cls, key, label);
    k_fsel<<<NB, 1024, 0, stream>>>(key, validCnt, candCount, cand);
    k_rankdec<<<dim3(CCAP / 512, NB), 256, 0, stream>>>(cand, candCount, label, boxp, anchors,
                                                        topBox, topScore, topLabel);
    k_maskT<<<dim3(136, NB), 64, 0, stream>>>(topBox, topLabel, maskT);
    k_nmsout<<<NB, 64, 0, stream>>>(maskT, validCnt, topBox, topScore, topLabel, out);
}